// Round 6
// baseline (494.049 us; speedup 1.0000x reference)
//
#include <hip/hip_runtime.h>
#include <hip/hip_bf16.h>
#include <stdint.h>

#define E_ 8
#define H_ 2048
#define I_ 1408
#define T_ 2048
#define K_ 2
#define G_ 128

typedef __bf16 bf16;
typedef bf16 bf16x8 __attribute__((ext_vector_type(8)));
typedef float f32x4 __attribute__((ext_vector_type(4)));

__device__ __forceinline__ uint32_t prm(uint32_t hi, uint32_t lo, uint32_t sel) {
    return __builtin_amdgcn_perm(hi, lo, sel);
}

// Scale-folded dequant tables: bf16(e2m1[m]*s) split into high/low byte LUTs.
struct DequantTab { uint32_t thi0, thi1, tlo0, tlo1; };

__device__ __forceinline__ DequantTab build_tab(float s) {
    union { bf16 h[8]; uint32_t u[4]; } tb;
    tb.h[0] = (bf16)(0.0f);
    tb.h[1] = (bf16)(0.5f * s);
    tb.h[2] = (bf16)(1.0f * s);
    tb.h[3] = (bf16)(1.5f * s);
    tb.h[4] = (bf16)(2.0f * s);
    tb.h[5] = (bf16)(3.0f * s);
    tb.h[6] = (bf16)(4.0f * s);
    tb.h[7] = (bf16)(6.0f * s);
    DequantTab t;
    t.thi0 = prm(tb.u[1], tb.u[0], 0x07050301u);
    t.tlo0 = prm(tb.u[1], tb.u[0], 0x06040200u);
    t.thi1 = prm(tb.u[3], tb.u[2], 0x07050301u);
    t.tlo1 = prm(tb.u[3], tb.u[2], 0x06040200u);
    return t;
}

// 8 fp4 (one u32, k-order) -> 8 scaled bf16 (B-fragment). ~21 VALU ops.
__device__ __forceinline__ bf16x8 dequant8t(uint32_t p, const DequantTab& t) {
    const uint32_t pr = p >> 4;
    const uint32_t pe = p  & 0x07070707u;
    const uint32_t po = pr & 0x07070707u;
    const uint32_t He = prm(t.thi1, t.thi0, pe) | ((p  & 0x08080808u) << 4);
    const uint32_t Le = prm(t.tlo1, t.tlo0, pe);
    const uint32_t Ho = prm(t.thi1, t.thi0, po) | ((pr & 0x08080808u) << 4);
    const uint32_t Lo = prm(t.tlo1, t.tlo0, po);
    const uint32_t E01 = prm(He, Le, 0x05010400u);
    const uint32_t E23 = prm(He, Le, 0x07030602u);
    const uint32_t O01 = prm(Ho, Lo, 0x05010400u);
    const uint32_t O23 = prm(Ho, Lo, 0x07030602u);
    union { uint4 u; bf16x8 v; } r;
    r.u = make_uint4(prm(O01, E01, 0x05040100u),
                     prm(O01, E01, 0x07060302u),
                     prm(O23, E23, 0x05040100u),
                     prm(O23, E23, 0x07060302u));
    return r.v;
}

// ---------------- routing ----------------
__global__ void route_count(const int* __restrict__ topk_idx, int* __restrict__ counts) {
    int p = blockIdx.x * blockDim.x + threadIdx.x;
    if (p < T_ * K_) atomicAdd(&counts[topk_idx[p]], 1);
}

// tiles of 64 tokens
__global__ void route_scan(const int* __restrict__ counts, int* __restrict__ offsets,
                           int* __restrict__ tmap) {
    if (threadIdx.x == 0) {
        int acc = 0, ti = 0;
        for (int e = 0; e < E_; e++) {
            offsets[e] = acc;
            int nt = (counts[e] + 63) >> 6;
            for (int j = 0; j < nt; j++) tmap[ti++] = (e << 16) | j;
            acc += counts[e];
        }
        offsets[E_] = acc;
        for (; ti < 128; ti++) tmap[ti] = -1;
    }
}

__global__ void route_fill(const int* __restrict__ topk_idx, const float* __restrict__ topk_w,
                           int* __restrict__ cursors, const int* __restrict__ offsets,
                           int* __restrict__ tok, float* __restrict__ wgt,
                           int* __restrict__ inv) {
    int p = blockIdx.x * blockDim.x + threadIdx.x;
    if (p < T_ * K_) {
        int e = topk_idx[p];
        int slot = atomicAdd(&cursors[e], 1);
        int idx = offsets[e] + slot;
        tok[idx] = p / K_;
        wgt[idx] = topk_w[p];
        inv[p] = idx;
    }
}

// x f32 -> bf16
__global__ __launch_bounds__(256)
void xcast_kernel(const float* __restrict__ x, uint4* __restrict__ xb) {
    const int i = blockIdx.x * 256 + threadIdx.x;
    const float4 a = ((const float4*)x)[i * 2];
    const float4 b = ((const float4*)x)[i * 2 + 1];
    union { uint4 u; bf16 h[8]; } r;
    r.h[0] = (bf16)a.x; r.h[1] = (bf16)a.y; r.h[2] = (bf16)a.z; r.h[3] = (bf16)a.w;
    r.h[4] = (bf16)b.x; r.h[5] = (bf16)b.y; r.h[6] = (bf16)b.z; r.h[7] = (bf16)b.w;
    xb[i] = r.u;
}

// ---------------- GEMM1 (register-resident, barrier-free) ----------------
// Block = 4 independent waves. Wave: 64 tokens x 32 i-cols, gate+up.
// A-frags and packed-B u32s loaded straight from global (L2/L3-resident),
// dequant in-register, 1-step explicit prefetch. No LDS, no barriers.
__global__ __launch_bounds__(256, 2)
void gemm1r_kernel(const bf16* __restrict__ xb,
                   const uint32_t* __restrict__ gate_packed,
                   const float* __restrict__ gate_scales,
                   const uint32_t* __restrict__ up_packed,
                   const float* __restrict__ up_scales,
                   const int* __restrict__ offsets,
                   const int* __restrict__ tmap,
                   const int* __restrict__ tok, bf16* __restrict__ h_buf)
{
    const int tm = tmap[blockIdx.y];
    if (tm < 0) return;
    const int e = tm >> 16, ty = tm & 0xffff;       // ty: 64-token tile
    const int row0 = offsets[e];
    const int cnt = offsets[e + 1] - row0;
    const int itile = blockIdx.x;                    // 128 i-cols per block

    const int tid = threadIdx.x;
    const int wave = tid >> 6, lane = tid & 63;
    const int lrow = lane & 15, kq = lane >> 4;

    // B rows (i-dim) owned by this lane: two 16-row fragments
    const int irow0 = itile * 128 + wave * 32 + lrow;
    const int irow1 = irow0 + 16;
    const uint32_t* gp0 = gate_packed + (size_t)e * I_ * (H_ / 8) + (size_t)irow0 * (H_ / 8) + kq;
    const uint32_t* gp1 = gate_packed + (size_t)e * I_ * (H_ / 8) + (size_t)irow1 * (H_ / 8) + kq;
    const uint32_t* up0 = up_packed + (size_t)e * I_ * (H_ / 8) + (size_t)irow0 * (H_ / 8) + kq;
    const uint32_t* up1 = up_packed + (size_t)e * I_ * (H_ / 8) + (size_t)irow1 * (H_ / 8) + kq;
    const float* gs_b = gate_scales + (size_t)e * (H_ / G_) * I_;
    const float* us_b = up_scales + (size_t)e * (H_ / G_) * I_;

    // A pointers: token rows ty*64 + mi*16 + lrow (clamped)
    const bf16* xa[4];
#pragma unroll
    for (int mi = 0; mi < 4; mi++) {
        int r = ty * 64 + mi * 16 + lrow;
        int t = tok[row0 + ((r < cnt) ? r : (cnt - 1))];
        xa[mi] = xb + (size_t)t * H_ + kq * 8;
    }

    f32x4 accg[4][2] = {};
    f32x4 accu[4][2] = {};

    // prefetch step 0
    bf16x8 a_c[4];
#pragma unroll
    for (int mi = 0; mi < 4; mi++) a_c[mi] = *(const bf16x8*)(xa[mi]);
    uint32_t pg0_c = gp0[0], pg1_c = gp1[0], pu0_c = up0[0], pu1_c = up1[0];

    for (int kg = 0; kg < H_ / G_; kg++) {           // 16 groups x 4 steps of K=32
        const DequantTab tg0 = build_tab(gs_b[kg * I_ + irow0]);
        const DequantTab tg1 = build_tab(gs_b[kg * I_ + irow1]);
        const DequantTab tu0 = build_tab(us_b[kg * I_ + irow0]);
        const DequantTab tu1 = build_tab(us_b[kg * I_ + irow1]);
#pragma unroll
        for (int kk = 0; kk < 4; kk++) {
            const int k = kg * 4 + kk;
            const int kn = (k < 63) ? (k + 1) : 63;  // clamped prefetch (re-read ok)
            bf16x8 a_n[4];
#pragma unroll
            for (int mi = 0; mi < 4; mi++) a_n[mi] = *(const bf16x8*)(xa[mi] + kn * 32);
            const uint32_t pg0_n = gp0[kn * 4], pg1_n = gp1[kn * 4];
            const uint32_t pu0_n = up0[kn * 4], pu1_n = up1[kn * 4];

            const bf16x8 bg0 = dequant8t(pg0_c, tg0);
            const bf16x8 bg1 = dequant8t(pg1_c, tg1);
            const bf16x8 bu0 = dequant8t(pu0_c, tu0);
            const bf16x8 bu1 = dequant8t(pu1_c, tu1);
#pragma unroll
            for (int mi = 0; mi < 4; mi++) {
                accg[mi][0] = __builtin_amdgcn_mfma_f32_16x16x32_bf16(a_c[mi], bg0, accg[mi][0], 0, 0, 0);
                accg[mi][1] = __builtin_amdgcn_mfma_f32_16x16x32_bf16(a_c[mi], bg1, accg[mi][1], 0, 0, 0);
                accu[mi][0] = __builtin_amdgcn_mfma_f32_16x16x32_bf16(a_c[mi], bu0, accu[mi][0], 0, 0, 0);
                accu[mi][1] = __builtin_amdgcn_mfma_f32_16x16x32_bf16(a_c[mi], bu1, accu[mi][1], 0, 0, 0);
            }
#pragma unroll
            for (int mi = 0; mi < 4; mi++) a_c[mi] = a_n[mi];
            pg0_c = pg0_n; pg1_c = pg1_n; pu0_c = pu0_n; pu1_c = pu1_n;
        }
    }

    // epilogue: h = silu(g)*u. C layout: col=lane&15, row=(lane>>4)*4+r
#pragma unroll
    for (int mi = 0; mi < 4; mi++)
#pragma unroll
        for (int ni = 0; ni < 2; ni++) {
            const int icol = itile * 128 + wave * 32 + ni * 16 + lrow;
#pragma unroll
            for (int r = 0; r < 4; r++) {
                const int grow = ty * 64 + mi * 16 + kq * 4 + r;
                if (grow < cnt) {
                    const float gv = accg[mi][ni][r];
                    const float hv = gv / (1.f + __expf(-gv)) * accu[mi][ni][r];
                    h_buf[(size_t)(row0 + grow) * I_ + icol] = (bf16)hv;
                }
            }
        }
}

// ---------------- GEMM2 (register-resident, barrier-free) ----------------
// Wave: 64 tokens x 32 h-cols. yp = wgt * (h @ Wd^T), plain stores.
__global__ __launch_bounds__(256, 3)
void gemm2r_kernel(const bf16* __restrict__ h_buf,
                   const uint32_t* __restrict__ down_packed,
                   const float* __restrict__ down_scales,
                   const int* __restrict__ offsets,
                   const int* __restrict__ tmap,
                   const float* __restrict__ wgt, float* __restrict__ yp)
{
    const int tm = tmap[blockIdx.y];
    if (tm < 0) return;
    const int e = tm >> 16, ty = tm & 0xffff;
    const int row0 = offsets[e];
    const int cnt = offsets[e + 1] - row0;
    const int htile = blockIdx.x;                    // 128 h-cols per block

    const int tid = threadIdx.x;
    const int wave = tid >> 6, lane = tid & 63;
    const int lrow = lane & 15, kq = lane >> 4;

    const int hrow0 = htile * 128 + wave * 32 + lrow;
    const int hrow1 = hrow0 + 16;
    const uint32_t* dp0 = down_packed + (size_t)e * H_ * (I_ / 8) + (size_t)hrow0 * (I_ / 8) + kq;
    const uint32_t* dp1 = down_packed + (size_t)e * H_ * (I_ / 8) + (size_t)hrow1 * (I_ / 8) + kq;
    const float* ds_b = down_scales + (size_t)e * (I_ / G_) * H_;

    const bf16* ha[4];
#pragma unroll
    for (int mi = 0; mi < 4; mi++) {
        int r = ty * 64 + mi * 16 + lrow;
        ha[mi] = h_buf + (size_t)(row0 + ((r < cnt) ? r : (cnt - 1))) * I_ + kq * 8;
    }

    f32x4 acc[4][2] = {};

    bf16x8 a_c[4];
#pragma unroll
    for (int mi = 0; mi < 4; mi++) a_c[mi] = *(const bf16x8*)(ha[mi]);
    uint32_t pd0_c = dp0[0], pd1_c = dp1[0];

    for (int kg = 0; kg < I_ / G_; kg++) {           // 11 groups x 4 steps
        const DequantTab td0 = build_tab(ds_b[kg * H_ + hrow0]);
        const DequantTab td1 = build_tab(ds_b[kg * H_ + hrow1]);
#pragma unroll
        for (int kk = 0; kk < 4; kk++) {
            const int k = kg * 4 + kk;
            const int kn = (k < 43) ? (k + 1) : 43;
            bf16x8 a_n[4];
#pragma unroll
            for (int mi = 0; mi < 4; mi++) a_n[mi] = *(const bf16x8*)(ha[mi] + kn * 32);
            const uint32_t pd0_n = dp0[kn * 4], pd1_n = dp1[kn * 4];

            const bf16x8 b0 = dequant8t(pd0_c, td0);
            const bf16x8 b1 = dequant8t(pd1_c, td1);
#pragma unroll
            for (int mi = 0; mi < 4; mi++) {
                acc[mi][0] = __builtin_amdgcn_mfma_f32_16x16x32_bf16(a_c[mi], b0, acc[mi][0], 0, 0, 0);
                acc[mi][1] = __builtin_amdgcn_mfma_f32_16x16x32_bf16(a_c[mi], b1, acc[mi][1], 0, 0, 0);
            }
#pragma unroll
            for (int mi = 0; mi < 4; mi++) a_c[mi] = a_n[mi];
            pd0_c = pd0_n; pd1_c = pd1_n;
        }
    }

    // epilogue: plain stores of wgt-scaled partials
#pragma unroll
    for (int mi = 0; mi < 4; mi++) {
#pragma unroll
        for (int r = 0; r < 4; r++) {
            const int grow = ty * 64 + mi * 16 + kq * 4 + r;
            if (grow < cnt) {
                const float w = wgt[row0 + grow];
#pragma unroll
                for (int ni = 0; ni < 2; ni++) {
                    const int col = htile * 128 + wave * 32 + ni * 16 + lrow;
                    yp[(size_t)(row0 + grow) * H_ + col] = acc[mi][ni][r] * w;
                }
            }
        }
    }
}

// ---------------- combine: out[t] = sum over K pairs ----------------
__global__ __launch_bounds__(256)
void combine_kernel(const float* __restrict__ yp, const int* __restrict__ inv,
                    float* __restrict__ out) {
    const int idx = blockIdx.x * 256 + threadIdx.x;   // T_*H_/4 units
    const int t = idx >> 9;                            // / (H_/4 = 512)
    const int c = idx & 511;
    const float4 a = ((const float4*)yp)[(size_t)inv[t * 2] * (H_ / 4) + c];
    const float4 b = ((const float4*)yp)[(size_t)inv[t * 2 + 1] * (H_ / 4) + c];
    float4 o;
    o.x = a.x + b.x; o.y = a.y + b.y; o.z = a.z + b.z; o.w = a.w + b.w;
    ((float4*)out)[idx] = o;
}

extern "C" void kernel_launch(void* const* d_in, const int* in_sizes, int n_in,
                              void* d_out, int out_size, void* d_ws, size_t ws_size,
                              hipStream_t stream) {
    const float* x = (const float*)d_in[0];
    const uint32_t* gate_packed = (const uint32_t*)d_in[1];
    const float* gate_scales = (const float*)d_in[2];
    const uint32_t* up_packed = (const uint32_t*)d_in[3];
    const float* up_scales = (const float*)d_in[4];
    const uint32_t* down_packed = (const uint32_t*)d_in[5];
    const float* down_scales = (const float*)d_in[6];
    const int* topk_idx = (const int*)d_in[7];
    const float* topk_w = (const float*)d_in[8];
    float* out = (float*)d_out;

    // workspace layout (bytes)
    char* ws = (char*)d_ws;
    int* counts  = (int*)ws;              // 32
    int* cursors = (int*)(ws + 32);       // 32
    int* offsets = (int*)(ws + 64);       // 64
    int* tmap    = (int*)(ws + 128);      // 512 (128 ints)
    int* tok     = (int*)(ws + 640);      // 16384
    float* wgt   = (float*)(ws + 17024);  // 16384
    int* inv     = (int*)(ws + 33408);    // 16384
    bf16* h_buf  = (bf16*)(ws + 49792);   // 11,534,336
    bf16* xb     = (bf16*)(ws + 49792 + 11534336ull);                 // 8,388,608
    float* yp    = (float*)(ws + 49792 + 11534336ull + 8388608ull);   // 33,554,432

    hipMemsetAsync(d_ws, 0, 1024, stream);

    route_count<<<(T_ * K_ + 255) / 256, 256, 0, stream>>>(topk_idx, counts);
    route_scan<<<1, 64, 0, stream>>>(counts, offsets, tmap);
    route_fill<<<(T_ * K_ + 255) / 256, 256, 0, stream>>>(topk_idx, topk_w, cursors, offsets,
                                                          tok, wgt, inv);
    xcast_kernel<<<T_ * H_ / 8 / 256, 256, 0, stream>>>(x, (uint4*)xb);

    dim3 g1(I_ / 128, 72);   // 11 x 72
    gemm1r_kernel<<<g1, 256, 0, stream>>>(xb, gate_packed, gate_scales, up_packed, up_scales,
                                          offsets, tmap, tok, h_buf);
    dim3 g2(H_ / 128, 72);   // 16 x 72
    gemm2r_kernel<<<g2, 256, 0, stream>>>(h_buf, down_packed, down_scales,
                                          offsets, tmap, wgt, yp);
    combine_kernel<<<T_ * H_ / 4 / 256, 256, 0, stream>>>(yp, inv, out);
}

// Round 7
// 306.300 us; speedup vs baseline: 1.6130x; 1.6130x over previous
//
#include <hip/hip_runtime.h>
#include <hip/hip_bf16.h>
#include <stdint.h>

#define E_ 8
#define H_ 2048
#define I_ 1408
#define T_ 2048
#define K_ 2
#define G_ 128

typedef __bf16 bf16;
typedef bf16 bf16x8 __attribute__((ext_vector_type(8)));
typedef float f32x4 __attribute__((ext_vector_type(4)));

__device__ __forceinline__ uint32_t prm(uint32_t hi, uint32_t lo, uint32_t sel) {
    return __builtin_amdgcn_perm(hi, lo, sel);
}

// Scale-folded dequant tables: bf16(e2m1[m]*s) split into high/low byte LUTs.
struct DequantTab { uint32_t thi0, thi1, tlo0, tlo1; };

__device__ __forceinline__ DequantTab build_tab(float s) {
    union { bf16 h[8]; uint32_t u[4]; } tb;
    tb.h[0] = (bf16)(0.0f);
    tb.h[1] = (bf16)(0.5f * s);
    tb.h[2] = (bf16)(1.0f * s);
    tb.h[3] = (bf16)(1.5f * s);
    tb.h[4] = (bf16)(2.0f * s);
    tb.h[5] = (bf16)(3.0f * s);
    tb.h[6] = (bf16)(4.0f * s);
    tb.h[7] = (bf16)(6.0f * s);
    DequantTab t;
    t.thi0 = prm(tb.u[1], tb.u[0], 0x07050301u);
    t.tlo0 = prm(tb.u[1], tb.u[0], 0x06040200u);
    t.thi1 = prm(tb.u[3], tb.u[2], 0x07050301u);
    t.tlo1 = prm(tb.u[3], tb.u[2], 0x06040200u);
    return t;
}

// 8 fp4 (one u32, k-order) -> 8 scaled bf16 as uint4. ~21 VALU ops.
__device__ __forceinline__ uint4 dequant8t(uint32_t p, const DequantTab& t) {
    const uint32_t pr = p >> 4;
    const uint32_t pe = p  & 0x07070707u;
    const uint32_t po = pr & 0x07070707u;
    const uint32_t He = prm(t.thi1, t.thi0, pe) | ((p  & 0x08080808u) << 4);
    const uint32_t Le = prm(t.tlo1, t.tlo0, pe);
    const uint32_t Ho = prm(t.thi1, t.thi0, po) | ((pr & 0x08080808u) << 4);
    const uint32_t Lo = prm(t.tlo1, t.tlo0, po);
    const uint32_t E01 = prm(He, Le, 0x05010400u);
    const uint32_t E23 = prm(He, Le, 0x07030602u);
    const uint32_t O01 = prm(Ho, Lo, 0x05010400u);
    const uint32_t O23 = prm(Ho, Lo, 0x07030602u);
    return make_uint4(prm(O01, E01, 0x05040100u),
                      prm(O01, E01, 0x07060302u),
                      prm(O23, E23, 0x05040100u),
                      prm(O23, E23, 0x07060302u));
}

// async 16B global -> LDS DMA (wave-uniform-base + lane-linear dest)
__device__ __forceinline__ void gld16(void* lds, const void* g) {
    __builtin_amdgcn_global_load_lds(
        (__attribute__((address_space(1))) void*)g,
        (__attribute__((address_space(3))) void*)lds, 16, 0, 0);
}

// ---------------- routing ----------------
__global__ void route_count(const int* __restrict__ topk_idx, int* __restrict__ counts) {
    int p = blockIdx.x * blockDim.x + threadIdx.x;
    if (p < T_ * K_) atomicAdd(&counts[topk_idx[p]], 1);
}

// tiles of 64 token-pairs
__global__ void route_scan(const int* __restrict__ counts, int* __restrict__ offsets,
                           int* __restrict__ tmap) {
    if (threadIdx.x == 0) {
        int acc = 0, ti = 0;
        for (int e = 0; e < E_; e++) {
            offsets[e] = acc;
            int nt = (counts[e] + 63) >> 6;
            for (int j = 0; j < nt; j++) tmap[ti++] = (e << 16) | j;
            acc += counts[e];
        }
        offsets[E_] = acc;
        for (; ti < 128; ti++) tmap[ti] = -1;
    }
}

__global__ void route_fill(const int* __restrict__ topk_idx, const float* __restrict__ topk_w,
                           int* __restrict__ cursors, const int* __restrict__ offsets,
                           int* __restrict__ tok, float* __restrict__ wgt,
                           int* __restrict__ inv) {
    int p = blockIdx.x * blockDim.x + threadIdx.x;
    if (p < T_ * K_) {
        int e = topk_idx[p];
        int slot = atomicAdd(&cursors[e], 1);
        int idx = offsets[e] + slot;
        tok[idx] = p / K_;
        wgt[idx] = topk_w[p];
        inv[p] = idx;
    }
}

// x f32 -> bf16
__global__ __launch_bounds__(256)
void xcast_kernel(const float* __restrict__ x, uint4* __restrict__ xb) {
    const int i = blockIdx.x * 256 + threadIdx.x;
    const float4 a = ((const float4*)x)[i * 2];
    const float4 b = ((const float4*)x)[i * 2 + 1];
    union { uint4 u; bf16 h[8]; } r;
    r.h[0] = (bf16)a.x; r.h[1] = (bf16)a.y; r.h[2] = (bf16)a.z; r.h[3] = (bf16)a.w;
    r.h[4] = (bf16)b.x; r.h[5] = (bf16)b.y; r.h[6] = (bf16)b.z; r.h[7] = (bf16)b.w;
    xb[i] = r.u;
}

// ---------------- GEMM1: 64tok x 64i tile, fused LUT dequant ----------------
// 4 waves 2x2 (tok-half x i-half); each wave 32x32 for BOTH gate & up
// => 8 MFMA/wave/step. ~1500 blocks (~5/CU) so barrier drains overlap
// across blocks.
__global__ __launch_bounds__(256, 4)
void gemm1t_kernel(const bf16* __restrict__ xb,
                   const uint32_t* __restrict__ gate_packed,
                   const float* __restrict__ gate_scales,
                   const uint32_t* __restrict__ up_packed,
                   const float* __restrict__ up_scales,
                   const int* __restrict__ offsets,
                   const int* __restrict__ tmap,
                   const int* __restrict__ tok, bf16* __restrict__ h_buf)
{
    const int tm = tmap[blockIdx.y];
    if (tm < 0) return;
    const int e = tm >> 16, ty = tm & 0xffff;       // 64-token tile
    const int row0 = offsets[e];
    const int cnt = offsets[e + 1] - row0;
    const int itile = blockIdx.x;                    // 64 i-cols

    __shared__ __align__(16) bf16 xs[64][32];
    __shared__ __align__(16) bf16 wgs[64][32];
    __shared__ __align__(16) bf16 wus[64][32];
    __shared__ int toks[64];

    const int tid = threadIdx.x;
    if (tid < 64) {
        int r = ty * 64 + tid;
        toks[tid] = tok[row0 + ((r < cnt) ? r : (cnt - 1))];
    }
    __syncthreads();

    const int srow = tid >> 2;          // 0..63
    const int scol = (tid & 3) * 8;
    const int wcol = tid & 3;
    const bf16* xg = xb + (size_t)toks[srow] * H_ + scol;
    bf16* lx = &xs[srow][scol];

    const int irow = itile * 64 + srow;
    const uint32_t* gp_row = gate_packed + (size_t)e * I_ * (H_ / 8) + (size_t)irow * (H_ / 8) + wcol;
    const uint32_t* up_row = up_packed + (size_t)e * I_ * (H_ / 8) + (size_t)irow * (H_ / 8) + wcol;
    const float* gs_row = gate_scales + (size_t)e * (H_ / G_) * I_ + irow;
    const float* us_row = up_scales + (size_t)e * (H_ / G_) * I_ + irow;
    uint4* lwg = (uint4*)&wgs[srow][wcol * 8];
    uint4* lwu = (uint4*)&wus[srow][wcol * 8];

    const int wave = tid >> 6, lane = tid & 63;
    const int wy = wave >> 1, wx = wave & 1;
    const int lrow = lane & 15, kq = lane >> 4;

    f32x4 accg[2][2] = {};
    f32x4 accu[2][2] = {};

    for (int kg = 0; kg < H_ / G_; kg++) {   // 16 groups x 4 steps of K=32
        const DequantTab tg = build_tab(gs_row[kg * I_]);
        const DequantTab tu = build_tab(us_row[kg * I_]);
#pragma unroll
        for (int kk = 0; kk < 4; kk++) {
            const int k0 = kg * 128 + kk * 32;
            gld16(lx, xg + k0);
            const uint32_t pg = gp_row[kg * 16 + kk * 4];
            const uint32_t pu = up_row[kg * 16 + kk * 4];
            *lwg = dequant8t(pg, tg);
            *lwu = dequant8t(pu, tu);
            __syncthreads();

            bf16x8 a[2], bg[2], bu[2];
#pragma unroll
            for (int mi = 0; mi < 2; mi++)
                a[mi] = *(const bf16x8*)&xs[wy * 32 + mi * 16 + lrow][kq * 8];
#pragma unroll
            for (int ni = 0; ni < 2; ni++) {
                bg[ni] = *(const bf16x8*)&wgs[wx * 32 + ni * 16 + lrow][kq * 8];
                bu[ni] = *(const bf16x8*)&wus[wx * 32 + ni * 16 + lrow][kq * 8];
            }
#pragma unroll
            for (int mi = 0; mi < 2; mi++)
#pragma unroll
                for (int ni = 0; ni < 2; ni++) {
                    accg[mi][ni] = __builtin_amdgcn_mfma_f32_16x16x32_bf16(a[mi], bg[ni], accg[mi][ni], 0, 0, 0);
                    accu[mi][ni] = __builtin_amdgcn_mfma_f32_16x16x32_bf16(a[mi], bu[ni], accu[mi][ni], 0, 0, 0);
                }
            __syncthreads();
        }
    }

    // epilogue: h = silu(g)*u. C layout: col=lane&15, row=(lane>>4)*4+r
#pragma unroll
    for (int mi = 0; mi < 2; mi++)
#pragma unroll
        for (int ni = 0; ni < 2; ni++) {
            const int icol = itile * 64 + wx * 32 + ni * 16 + lrow;
#pragma unroll
            for (int r = 0; r < 4; r++) {
                const int grow = ty * 64 + wy * 32 + mi * 16 + kq * 4 + r;
                if (grow < cnt) {
                    const float gv = accg[mi][ni][r];
                    const float hv = gv / (1.f + __expf(-gv)) * accu[mi][ni][r];
                    h_buf[(size_t)(row0 + grow) * I_ + icol] = (bf16)hv;
                }
            }
        }
}

// ---------------- GEMM2: 64tok x 128h tile -> yp (no atomics) ----------------
// 4 waves 2x2 (tok-half x h-half); wave 32tok x 64h => 8 MFMA/step.
__global__ __launch_bounds__(256, 4)
void gemm2t_kernel(const bf16* __restrict__ h_buf,
                   const uint32_t* __restrict__ down_packed,
                   const float* __restrict__ down_scales,
                   const int* __restrict__ offsets,
                   const int* __restrict__ tmap,
                   const float* __restrict__ wgt, float* __restrict__ yp)
{
    const int tm = tmap[blockIdx.y];
    if (tm < 0) return;
    const int e = tm >> 16, ty = tm & 0xffff;
    const int row0 = offsets[e];
    const int cnt = offsets[e + 1] - row0;
    const int htile = blockIdx.x;                    // 128 h-cols

    __shared__ __align__(16) bf16 hs[64][32];
    __shared__ __align__(16) bf16 wds[128][32];
    __shared__ float wgts[64];

    const int tid = threadIdx.x;
    if (tid < 64) {
        int r = ty * 64 + tid;
        wgts[tid] = (r < cnt) ? wgt[row0 + r] : 0.f;
    }
    __syncthreads();

    // h staging: 64 rows x 32 k, 16B per thread
    const int srow = tid >> 2;
    const int scol = (tid & 3) * 8;
    const int m0 = ty * 64 + srow;
    const int hr0 = row0 + ((m0 < cnt) ? m0 : (cnt - 1));
    const bf16* hg = h_buf + (size_t)hr0 * I_ + scol;
    bf16* lh = &hs[srow][scol];

    // weight staging: 128 rows x 32 k -> 2 u32 per thread
    const int srow2 = tid >> 1;
    const int wcol2 = (tid & 1) * 2;
    const int hrow = htile * 128 + srow2;
    const uint32_t* dp_row = down_packed + (size_t)e * H_ * (I_ / 8) + (size_t)hrow * (I_ / 8) + wcol2;
    const float* ds_row = down_scales + (size_t)e * (I_ / G_) * H_ + hrow;
    uint4* lwd0 = (uint4*)&wds[srow2][wcol2 * 8];
    uint4* lwd1 = (uint4*)&wds[srow2][wcol2 * 8 + 8];

    const int wave = tid >> 6, lane = tid & 63;
    const int wy = wave >> 1, wx = wave & 1;
    const int lrow = lane & 15, kq = lane >> 4;

    f32x4 acc[2][4] = {};

    for (int kg = 0; kg < I_ / G_; kg++) {   // 11 groups x 4 steps
        const DequantTab td = build_tab(ds_row[kg * H_]);
#pragma unroll
        for (int kk = 0; kk < 4; kk++) {
            const int k0 = kg * 128 + kk * 32;
            gld16(lh, hg + k0);
            const uint32_t pd0 = dp_row[kg * 16 + kk * 4];
            const uint32_t pd1 = dp_row[kg * 16 + kk * 4 + 1];
            *lwd0 = dequant8t(pd0, td);
            *lwd1 = dequant8t(pd1, td);
            __syncthreads();

            bf16x8 a[2], b[4];
#pragma unroll
            for (int mi = 0; mi < 2; mi++)
                a[mi] = *(const bf16x8*)&hs[wy * 32 + mi * 16 + lrow][kq * 8];
#pragma unroll
            for (int ni = 0; ni < 4; ni++)
                b[ni] = *(const bf16x8*)&wds[wx * 64 + ni * 16 + lrow][kq * 8];
#pragma unroll
            for (int mi = 0; mi < 2; mi++)
#pragma unroll
                for (int ni = 0; ni < 4; ni++)
                    acc[mi][ni] = __builtin_amdgcn_mfma_f32_16x16x32_bf16(a[mi], b[ni], acc[mi][ni], 0, 0, 0);
            __syncthreads();
        }
    }

    // epilogue: plain stores of wgt-scaled partials
#pragma unroll
    for (int mi = 0; mi < 2; mi++)
#pragma unroll
        for (int r = 0; r < 4; r++) {
            const int lr = wy * 32 + mi * 16 + kq * 4 + r;
            const int grow = ty * 64 + lr;
            if (grow < cnt) {
                const float w = wgts[lr];
#pragma unroll
                for (int ni = 0; ni < 4; ni++) {
                    const int col = htile * 128 + wx * 64 + ni * 16 + lrow;
                    yp[(size_t)(row0 + grow) * H_ + col] = acc[mi][ni][r] * w;
                }
            }
        }
}

// ---------------- combine: out[t] = sum over K pairs ----------------
__global__ __launch_bounds__(256)
void combine_kernel(const float* __restrict__ yp, const int* __restrict__ inv,
                    float* __restrict__ out) {
    const int idx = blockIdx.x * 256 + threadIdx.x;   // T_*H_/4 units
    const int t = idx >> 9;                            // / (H_/4 = 512)
    const int c = idx & 511;
    const float4 a = ((const float4*)yp)[(size_t)inv[t * 2] * (H_ / 4) + c];
    const float4 b = ((const float4*)yp)[(size_t)inv[t * 2 + 1] * (H_ / 4) + c];
    float4 o;
    o.x = a.x + b.x; o.y = a.y + b.y; o.z = a.z + b.z; o.w = a.w + b.w;
    ((float4*)out)[idx] = o;
}

extern "C" void kernel_launch(void* const* d_in, const int* in_sizes, int n_in,
                              void* d_out, int out_size, void* d_ws, size_t ws_size,
                              hipStream_t stream) {
    const float* x = (const float*)d_in[0];
    const uint32_t* gate_packed = (const uint32_t*)d_in[1];
    const float* gate_scales = (const float*)d_in[2];
    const uint32_t* up_packed = (const uint32_t*)d_in[3];
    const float* up_scales = (const float*)d_in[4];
    const uint32_t* down_packed = (const uint32_t*)d_in[5];
    const float* down_scales = (const float*)d_in[6];
    const int* topk_idx = (const int*)d_in[7];
    const float* topk_w = (const float*)d_in[8];
    float* out = (float*)d_out;

    // workspace layout (bytes)
    char* ws = (char*)d_ws;
    int* counts  = (int*)ws;              // 32
    int* cursors = (int*)(ws + 32);       // 32
    int* offsets = (int*)(ws + 64);       // 64
    int* tmap    = (int*)(ws + 128);      // 512 (128 ints)
    int* tok     = (int*)(ws + 640);      // 16384
    float* wgt   = (float*)(ws + 17024);  // 16384
    int* inv     = (int*)(ws + 33408);    // 16384
    bf16* h_buf  = (bf16*)(ws + 49792);   // 11,534,336
    bf16* xb     = (bf16*)(ws + 49792 + 11534336ull);                 // 8,388,608
    float* yp    = (float*)(ws + 49792 + 11534336ull + 8388608ull);   // 33,554,432

    hipMemsetAsync(d_ws, 0, 1024, stream);

    route_count<<<(T_ * K_ + 255) / 256, 256, 0, stream>>>(topk_idx, counts);
    route_scan<<<1, 64, 0, stream>>>(counts, offsets, tmap);
    route_fill<<<(T_ * K_ + 255) / 256, 256, 0, stream>>>(topk_idx, topk_w, cursors, offsets,
                                                          tok, wgt, inv);
    xcast_kernel<<<T_ * H_ / 8 / 256, 256, 0, stream>>>(x, (uint4*)xb);

    dim3 g1(I_ / 64, 72);    // 22 x 72 = 1584 blocks
    gemm1t_kernel<<<g1, 256, 0, stream>>>(xb, gate_packed, gate_scales, up_packed, up_scales,
                                          offsets, tmap, tok, h_buf);
    dim3 g2(H_ / 128, 72);   // 16 x 72 = 1152 blocks
    gemm2t_kernel<<<g2, 256, 0, stream>>>(h_buf, down_packed, down_scales,
                                          offsets, tmap, wgt, yp);
    combine_kernel<<<T_ * H_ / 4 / 256, 256, 0, stream>>>(yp, inv, out);
}

// Round 8
// 288.203 us; speedup vs baseline: 1.7142x; 1.0628x over previous
//
#include <hip/hip_runtime.h>
#include <hip/hip_bf16.h>
#include <stdint.h>

#define E_ 8
#define H_ 2048
#define I_ 1408
#define T_ 2048
#define K_ 2
#define G_ 128

typedef __bf16 bf16;
typedef bf16 bf16x8 __attribute__((ext_vector_type(8)));
typedef float f32x4 __attribute__((ext_vector_type(4)));

__device__ __forceinline__ uint32_t prm(uint32_t hi, uint32_t lo, uint32_t sel) {
    return __builtin_amdgcn_perm(hi, lo, sel);
}

// Scale-folded dequant tables: bf16(e2m1[m]*s) split into high/low byte LUTs.
struct DequantTab { uint32_t thi0, thi1, tlo0, tlo1; };

__device__ __forceinline__ DequantTab build_tab(float s) {
    union { bf16 h[8]; uint32_t u[4]; } tb;
    tb.h[0] = (bf16)(0.0f);
    tb.h[1] = (bf16)(0.5f * s);
    tb.h[2] = (bf16)(1.0f * s);
    tb.h[3] = (bf16)(1.5f * s);
    tb.h[4] = (bf16)(2.0f * s);
    tb.h[5] = (bf16)(3.0f * s);
    tb.h[6] = (bf16)(4.0f * s);
    tb.h[7] = (bf16)(6.0f * s);
    DequantTab t;
    t.thi0 = prm(tb.u[1], tb.u[0], 0x07050301u);
    t.tlo0 = prm(tb.u[1], tb.u[0], 0x06040200u);
    t.thi1 = prm(tb.u[3], tb.u[2], 0x07050301u);
    t.tlo1 = prm(tb.u[3], tb.u[2], 0x06040200u);
    return t;
}

// 8 fp4 (one u32, k-order) -> 8 scaled bf16 as uint4. ~21 VALU ops.
__device__ __forceinline__ uint4 dequant8t(uint32_t p, const DequantTab& t) {
    const uint32_t pr = p >> 4;
    const uint32_t pe = p  & 0x07070707u;
    const uint32_t po = pr & 0x07070707u;
    const uint32_t He = prm(t.thi1, t.thi0, pe) | ((p  & 0x08080808u) << 4);
    const uint32_t Le = prm(t.tlo1, t.tlo0, pe);
    const uint32_t Ho = prm(t.thi1, t.thi0, po) | ((pr & 0x08080808u) << 4);
    const uint32_t Lo = prm(t.tlo1, t.tlo0, po);
    const uint32_t E01 = prm(He, Le, 0x05010400u);
    const uint32_t E23 = prm(He, Le, 0x07030602u);
    const uint32_t O01 = prm(Ho, Lo, 0x05010400u);
    const uint32_t O23 = prm(Ho, Lo, 0x07030602u);
    return make_uint4(prm(O01, E01, 0x05040100u),
                      prm(O01, E01, 0x07060302u),
                      prm(O23, E23, 0x05040100u),
                      prm(O23, E23, 0x07060302u));
}

// async 16B global -> LDS DMA (wave-uniform-base + lane-linear dest)
__device__ __forceinline__ void gld16(void* lds, const void* g) {
    __builtin_amdgcn_global_load_lds(
        (__attribute__((address_space(1))) void*)g,
        (__attribute__((address_space(3))) void*)lds, 16, 0, 0);
}

// ---------------- routing ----------------
__global__ void route_count(const int* __restrict__ topk_idx, int* __restrict__ counts) {
    int p = blockIdx.x * blockDim.x + threadIdx.x;
    if (p < T_ * K_) atomicAdd(&counts[topk_idx[p]], 1);
}

// tiles of 64 token-pairs
__global__ void route_scan(const int* __restrict__ counts, int* __restrict__ offsets,
                           int* __restrict__ tmap) {
    if (threadIdx.x == 0) {
        int acc = 0, ti = 0;
        for (int e = 0; e < E_; e++) {
            offsets[e] = acc;
            int nt = (counts[e] + 63) >> 6;
            for (int j = 0; j < nt; j++) tmap[ti++] = (e << 16) | j;
            acc += counts[e];
        }
        offsets[E_] = acc;
        for (; ti < 128; ti++) tmap[ti] = -1;
    }
}

__global__ void route_fill(const int* __restrict__ topk_idx, const float* __restrict__ topk_w,
                           int* __restrict__ cursors, const int* __restrict__ offsets,
                           int* __restrict__ tok, float* __restrict__ wgt,
                           int* __restrict__ inv) {
    int p = blockIdx.x * blockDim.x + threadIdx.x;
    if (p < T_ * K_) {
        int e = topk_idx[p];
        int slot = atomicAdd(&cursors[e], 1);
        int idx = offsets[e] + slot;
        tok[idx] = p / K_;
        wgt[idx] = topk_w[p];
        inv[p] = idx;
    }
}

// x f32 -> bf16
__global__ __launch_bounds__(256)
void xcast_kernel(const float* __restrict__ x, uint4* __restrict__ xb) {
    const int i = blockIdx.x * 256 + threadIdx.x;
    const float4 a = ((const float4*)x)[i * 2];
    const float4 b = ((const float4*)x)[i * 2 + 1];
    union { uint4 u; bf16 h[8]; } r;
    r.h[0] = (bf16)a.x; r.h[1] = (bf16)a.y; r.h[2] = (bf16)a.z; r.h[3] = (bf16)a.w;
    r.h[4] = (bf16)b.x; r.h[5] = (bf16)b.y; r.h[6] = (bf16)b.z; r.h[7] = (bf16)b.w;
    xb[i] = r.u;
}

// ---------------- GEMM1: 64tok x 64i tile, BK=64, swizzled LDS ----------------
// grid: x = token-tile (tmap), y = itile  -> weight-tile L3/L2 reuse.
// LDS chunk swizzle: 16B chunk c of row r stored at chunk c^(r&7).
__global__ __launch_bounds__(256, 4)
void gemm1t_kernel(const bf16* __restrict__ xb,
                   const uint32_t* __restrict__ gate_packed,
                   const float* __restrict__ gate_scales,
                   const uint32_t* __restrict__ up_packed,
                   const float* __restrict__ up_scales,
                   const int* __restrict__ offsets,
                   const int* __restrict__ tmap,
                   const int* __restrict__ tok, bf16* __restrict__ h_buf)
{
    const int tm = tmap[blockIdx.x];
    if (tm < 0) return;
    const int e = tm >> 16, ty = tm & 0xffff;       // 64-token tile
    const int row0 = offsets[e];
    const int cnt = offsets[e + 1] - row0;
    const int itile = blockIdx.y;                    // 64 i-cols

    __shared__ __align__(16) bf16 xs[64][64];
    __shared__ __align__(16) bf16 wgs[64][64];
    __shared__ __align__(16) bf16 wus[64][64];

    const int tid = threadIdx.x;

    // --- x staging roles: 2 gld16/thread/step, swizzled source chunk ---
    const int xr0 = tid >> 3;            // 0..31
    const int xr1 = xr0 + 32;
    const int xc  = tid & 7;             // dest chunk
    int g0 = ty * 64 + xr0;  g0 = (g0 < cnt) ? g0 : (cnt - 1);
    int g1 = ty * 64 + xr1;  g1 = (g1 < cnt) ? g1 : (cnt - 1);
    const bf16* xsrc0 = xb + (size_t)tok[row0 + g0] * H_ + ((xc ^ (xr0 & 7)) * 8);
    const bf16* xsrc1 = xb + (size_t)tok[row0 + g1] * H_ + ((xc ^ (xr1 & 7)) * 8);
    bf16* xdst0 = &xs[xr0][xc * 8];      // lane-linear: tid*16B
    bf16* xdst1 = &xs[xr1][xc * 8];

    // --- weight staging roles: 1 uint4 (4 u32 = 32 fp4) per thread/step ---
    const int mat  = tid >> 7;           // 0 = gate, 1 = up
    const int id   = tid & 127;
    const int wrow = id >> 1;            // 0..63
    const int quad = id & 1;             // u32 group {0..3} or {4..7}
    const int irow = itile * 64 + wrow;
    const uint32_t* wp_row = (mat ? up_packed : gate_packed)
        + (size_t)e * I_ * (H_ / 8) + (size_t)irow * (H_ / 8) + quad * 4;
    const float* ws_row = (mat ? up_scales : gate_scales)
        + (size_t)e * (H_ / G_) * I_ + irow;
    bf16 (* const wdst)[64] = mat ? wus : wgs;

    const int wave = tid >> 6, lane = tid & 63;
    const int wy = wave >> 1, wx = wave & 1;
    const int lrow = lane & 15, kq = lane >> 4;

    f32x4 accg[2][2] = {};
    f32x4 accu[2][2] = {};

    for (int kg = 0; kg < H_ / G_; kg++) {          // 16 groups = 2 BK64 steps each
        const DequantTab tw = build_tab(ws_row[kg * I_]);
#pragma unroll
        for (int kh2 = 0; kh2 < 2; kh2++) {
            const int k0 = kg * 128 + kh2 * 64;
            gld16(xdst0, xsrc0 + k0);
            gld16(xdst1, xsrc1 + k0);
            const uint4 pw = *(const uint4*)(wp_row + (k0 >> 3));
            {
                uint4 d0 = dequant8t(pw.x, tw);
                uint4 d1 = dequant8t(pw.y, tw);
                uint4 d2 = dequant8t(pw.z, tw);
                uint4 d3 = dequant8t(pw.w, tw);
                const int cb = quad * 4, rs = wrow & 7;
                *(uint4*)&wdst[wrow][((cb + 0) ^ rs) * 8] = d0;
                *(uint4*)&wdst[wrow][((cb + 1) ^ rs) * 8] = d1;
                *(uint4*)&wdst[wrow][((cb + 2) ^ rs) * 8] = d2;
                *(uint4*)&wdst[wrow][((cb + 3) ^ rs) * 8] = d3;
            }
            __syncthreads();

#pragma unroll
            for (int kh = 0; kh < 2; kh++) {        // two K=32 slices
                bf16x8 a[2], bg[2], bu[2];
#pragma unroll
                for (int mi = 0; mi < 2; mi++) {
                    const int ra = wy * 32 + mi * 16 + lrow;
                    a[mi] = *(const bf16x8*)&xs[ra][((kh * 4 + kq) ^ (ra & 7)) * 8];
                }
#pragma unroll
                for (int ni = 0; ni < 2; ni++) {
                    const int rb = wx * 32 + ni * 16 + lrow;
                    const int cb = ((kh * 4 + kq) ^ (rb & 7)) * 8;
                    bg[ni] = *(const bf16x8*)&wgs[rb][cb];
                    bu[ni] = *(const bf16x8*)&wus[rb][cb];
                }
#pragma unroll
                for (int mi = 0; mi < 2; mi++)
#pragma unroll
                    for (int ni = 0; ni < 2; ni++) {
                        accg[mi][ni] = __builtin_amdgcn_mfma_f32_16x16x32_bf16(a[mi], bg[ni], accg[mi][ni], 0, 0, 0);
                        accu[mi][ni] = __builtin_amdgcn_mfma_f32_16x16x32_bf16(a[mi], bu[ni], accu[mi][ni], 0, 0, 0);
                    }
            }
            __syncthreads();
        }
    }

    // epilogue: h = silu(g)*u. C layout: col=lane&15, row=(lane>>4)*4+r
#pragma unroll
    for (int mi = 0; mi < 2; mi++)
#pragma unroll
        for (int ni = 0; ni < 2; ni++) {
            const int icol = itile * 64 + wx * 32 + ni * 16 + lrow;
#pragma unroll
            for (int r = 0; r < 4; r++) {
                const int grow = ty * 64 + wy * 32 + mi * 16 + kq * 4 + r;
                if (grow < cnt) {
                    const float gv = accg[mi][ni][r];
                    const float hv = gv / (1.f + __expf(-gv)) * accu[mi][ni][r];
                    h_buf[(size_t)(row0 + grow) * I_ + icol] = (bf16)hv;
                }
            }
        }
}

// ---------------- GEMM2: 64tok x 128h tile, BK=64, swizzled -> yp ----------------
__global__ __launch_bounds__(256, 4)
void gemm2t_kernel(const bf16* __restrict__ h_buf,
                   const uint32_t* __restrict__ down_packed,
                   const float* __restrict__ down_scales,
                   const int* __restrict__ offsets,
                   const int* __restrict__ tmap,
                   const float* __restrict__ wgt, float* __restrict__ yp)
{
    const int tm = tmap[blockIdx.x];
    if (tm < 0) return;
    const int e = tm >> 16, ty = tm & 0xffff;
    const int row0 = offsets[e];
    const int cnt = offsets[e + 1] - row0;
    const int htile = blockIdx.y;                    // 128 h-cols

    __shared__ __align__(16) bf16 hs[64][64];
    __shared__ __align__(16) bf16 wds[128][64];

    const int tid = threadIdx.x;

    // --- h staging: 2 gld16/thread/step ---
    const int xr0 = tid >> 3;
    const int xr1 = xr0 + 32;
    const int xc  = tid & 7;
    int g0 = ty * 64 + xr0;  g0 = (g0 < cnt) ? g0 : (cnt - 1);
    int g1 = ty * 64 + xr1;  g1 = (g1 < cnt) ? g1 : (cnt - 1);
    const bf16* hsrc0 = h_buf + (size_t)(row0 + g0) * I_ + ((xc ^ (xr0 & 7)) * 8);
    const bf16* hsrc1 = h_buf + (size_t)(row0 + g1) * I_ + ((xc ^ (xr1 & 7)) * 8);
    bf16* hdst0 = &hs[xr0][xc * 8];
    bf16* hdst1 = &hs[xr1][xc * 8];

    // --- weight staging: 128 rows x 8 u32 -> 1 uint4 per thread/step ---
    const int wrow = tid >> 1;           // 0..127
    const int quad = tid & 1;
    const int hrow = htile * 128 + wrow;
    const uint32_t* dp_row = down_packed + (size_t)e * H_ * (I_ / 8) + (size_t)hrow * (I_ / 8) + quad * 4;
    const float* ds_row = down_scales + (size_t)e * (I_ / G_) * H_ + hrow;

    const int wave = tid >> 6, lane = tid & 63;
    const int wy = wave >> 1, wx = wave & 1;
    const int lrow = lane & 15, kq = lane >> 4;

    f32x4 acc[2][4] = {};

    for (int kg = 0; kg < I_ / G_; kg++) {          // 11 groups = 2 BK64 steps each
        const DequantTab td = build_tab(ds_row[kg * H_]);
#pragma unroll
        for (int kh2 = 0; kh2 < 2; kh2++) {
            const int k0 = kg * 128 + kh2 * 64;
            gld16(hdst0, hsrc0 + k0);
            gld16(hdst1, hsrc1 + k0);
            const uint4 pw = *(const uint4*)(dp_row + (k0 >> 3));
            {
                uint4 d0 = dequant8t(pw.x, td);
                uint4 d1 = dequant8t(pw.y, td);
                uint4 d2 = dequant8t(pw.z, td);
                uint4 d3 = dequant8t(pw.w, td);
                const int cb = quad * 4, rs = wrow & 7;
                *(uint4*)&wds[wrow][((cb + 0) ^ rs) * 8] = d0;
                *(uint4*)&wds[wrow][((cb + 1) ^ rs) * 8] = d1;
                *(uint4*)&wds[wrow][((cb + 2) ^ rs) * 8] = d2;
                *(uint4*)&wds[wrow][((cb + 3) ^ rs) * 8] = d3;
            }
            __syncthreads();

#pragma unroll
            for (int kh = 0; kh < 2; kh++) {
                bf16x8 a[2], b[4];
#pragma unroll
                for (int mi = 0; mi < 2; mi++) {
                    const int ra = wy * 32 + mi * 16 + lrow;
                    a[mi] = *(const bf16x8*)&hs[ra][((kh * 4 + kq) ^ (ra & 7)) * 8];
                }
#pragma unroll
                for (int ni = 0; ni < 4; ni++) {
                    const int rb = wx * 64 + ni * 16 + lrow;
                    b[ni] = *(const bf16x8*)&wds[rb][((kh * 4 + kq) ^ (rb & 7)) * 8];
                }
#pragma unroll
                for (int mi = 0; mi < 2; mi++)
#pragma unroll
                    for (int ni = 0; ni < 4; ni++)
                        acc[mi][ni] = __builtin_amdgcn_mfma_f32_16x16x32_bf16(a[mi], b[ni], acc[mi][ni], 0, 0, 0);
            }
            __syncthreads();
        }
    }

    // epilogue: plain stores of wgt-scaled partials
#pragma unroll
    for (int mi = 0; mi < 2; mi++)
#pragma unroll
        for (int r = 0; r < 4; r++) {
            const int lr = wy * 32 + mi * 16 + kq * 4 + r;
            const int grow = ty * 64 + lr;
            if (grow < cnt) {
                const float w = wgt[row0 + grow];
#pragma unroll
                for (int ni = 0; ni < 4; ni++) {
                    const int col = htile * 128 + wx * 64 + ni * 16 + lrow;
                    yp[(size_t)(row0 + grow) * H_ + col] = acc[mi][ni][r] * w;
                }
            }
        }
}

// ---------------- combine: out[t] = sum over K pairs ----------------
__global__ __launch_bounds__(256)
void combine_kernel(const float* __restrict__ yp, const int* __restrict__ inv,
                    float* __restrict__ out) {
    const int idx = blockIdx.x * 256 + threadIdx.x;   // T_*H_/4 units
    const int t = idx >> 9;                            // / (H_/4 = 512)
    const int c = idx & 511;
    const float4 a = ((const float4*)yp)[(size_t)inv[t * 2] * (H_ / 4) + c];
    const float4 b = ((const float4*)yp)[(size_t)inv[t * 2 + 1] * (H_ / 4) + c];
    float4 o;
    o.x = a.x + b.x; o.y = a.y + b.y; o.z = a.z + b.z; o.w = a.w + b.w;
    ((float4*)out)[idx] = o;
}

extern "C" void kernel_launch(void* const* d_in, const int* in_sizes, int n_in,
                              void* d_out, int out_size, void* d_ws, size_t ws_size,
                              hipStream_t stream) {
    const float* x = (const float*)d_in[0];
    const uint32_t* gate_packed = (const uint32_t*)d_in[1];
    const float* gate_scales = (const float*)d_in[2];
    const uint32_t* up_packed = (const uint32_t*)d_in[3];
    const float* up_scales = (const float*)d_in[4];
    const uint32_t* down_packed = (const uint32_t*)d_in[5];
    const float* down_scales = (const float*)d_in[6];
    const int* topk_idx = (const int*)d_in[7];
    const float* topk_w = (const float*)d_in[8];
    float* out = (float*)d_out;

    // workspace layout (bytes)
    char* ws = (char*)d_ws;
    int* counts  = (int*)ws;              // 32
    int* cursors = (int*)(ws + 32);       // 32
    int* offsets = (int*)(ws + 64);       // 64
    int* tmap    = (int*)(ws + 128);      // 512 (128 ints)
    int* tok     = (int*)(ws + 640);      // 16384
    float* wgt   = (float*)(ws + 17024);  // 16384
    int* inv     = (int*)(ws + 33408);    // 16384
    bf16* h_buf  = (bf16*)(ws + 49792);   // 11,534,336
    bf16* xb     = (bf16*)(ws + 49792 + 11534336ull);                 // 8,388,608
    float* yp    = (float*)(ws + 49792 + 11534336ull + 8388608ull);   // 33,554,432

    hipMemsetAsync(d_ws, 0, 1024, stream);

    route_count<<<(T_ * K_ + 255) / 256, 256, 0, stream>>>(topk_idx, counts);
    route_scan<<<1, 64, 0, stream>>>(counts, offsets, tmap);
    route_fill<<<(T_ * K_ + 255) / 256, 256, 0, stream>>>(topk_idx, topk_w, cursors, offsets,
                                                          tok, wgt, inv);
    xcast_kernel<<<T_ * H_ / 8 / 256, 256, 0, stream>>>(x, (uint4*)xb);

    dim3 g1(72, I_ / 64);    // x = token-tile (weight reuse), y = itile
    gemm1t_kernel<<<g1, 256, 0, stream>>>(xb, gate_packed, gate_scales, up_packed, up_scales,
                                          offsets, tmap, tok, h_buf);
    dim3 g2(72, H_ / 128);   // x = token-tile, y = htile
    gemm2t_kernel<<<g2, 256, 0, stream>>>(h_buf, down_packed, down_scales,
                                          offsets, tmap, wgt, yp);
    combine_kernel<<<T_ * H_ / 4 / 256, 256, 0, stream>>>(yp, inv, out);
}